// Round 2
// baseline (1827.746 us; speedup 1.0000x reference)
//
#include <hip/hip_runtime.h>
#include <hip/hip_bf16.h>
#include <stdint.h>

typedef __bf16 bf16_t;
typedef __bf16 bf16x4 __attribute__((ext_vector_type(4)));
typedef __bf16 bf16x8 __attribute__((ext_vector_type(8)));
typedef float f32x4 __attribute__((ext_vector_type(4)));

#define LDS_CAST(p) ((__attribute__((address_space(3))) void*)(p))
#define GLB_CAST(p) ((const __attribute__((address_space(1))) void*)(p))

__device__ __forceinline__ void gl_lds16(const void* g, void* l) {
  __builtin_amdgcn_global_load_lds(GLB_CAST(g), LDS_CAST(l), 16, 0, 0);
}

static constexpr int M_TOT = 2 * 2048;   // B*S = 4096
static constexpr int H_DIM = 4096;
static constexpr int I_DIM = 14336;

// ---------------------------------------------------------------------------
// fp32 -> bf16 conversion, vectorized (float4 in, bf16x4 out), grid-stride
// ---------------------------------------------------------------------------
__global__ __launch_bounds__(256)
void k_conv(const float4* __restrict__ src, bf16x4* __restrict__ dst, long n4)
{
  long stride = (long)gridDim.x * blockDim.x;
  for (long i = (long)blockIdx.x * blockDim.x + threadIdx.x; i < n4; i += stride) {
    float4 v = src[i];
    bf16x4 o;
    o[0] = (bf16_t)v.x; o[1] = (bf16_t)v.y; o[2] = (bf16_t)v.z; o[3] = (bf16_t)v.w;
    dst[i] = o;
  }
}

// ---------------------------------------------------------------------------
// Kernel 1: A[M,I] = silu(X Wg^T) * (X Wu^T)   (bf16 in, bf16 out)
// 128x128 tile, BK=32, 4 waves (2x2), dual accumulators, silu*mul epilogue.
// ---------------------------------------------------------------------------
__global__ __launch_bounds__(256, 2)
void k_gateup(const bf16_t* __restrict__ X, const bf16_t* __restrict__ Wg,
              const bf16_t* __restrict__ Wu, bf16_t* __restrict__ A)
{
  __shared__ bf16_t Xs[128 * 32];
  __shared__ bf16_t Gs[128 * 32];
  __shared__ bf16_t Us[128 * 32];

  const int tid  = threadIdx.x;
  const int wave = tid >> 6;
  const int lane = tid & 63;

  const int TN = I_DIM / 128;              // 112
  const int tm = blockIdx.x / TN;
  const int tn = blockIdx.x % TN;

  const int srow = tid >> 2;               // 0..63
  const int scol = (tid & 3) * 8;

  const bf16_t* gX = X  + (size_t)(tm * 128 + srow) * H_DIM + scol;
  const bf16_t* gG = Wg + (size_t)(tn * 128 + srow) * H_DIM + scol;
  const bf16_t* gU = Wu + (size_t)(tn * 128 + srow) * H_DIM + scol;
  const size_t half = (size_t)64 * H_DIM;

  char* ldsX = (char*)Xs + wave * 1024;
  char* ldsG = (char*)Gs + wave * 1024;
  char* ldsU = (char*)Us + wave * 1024;

  const f32x4 vzero = {0.f, 0.f, 0.f, 0.f};
  f32x4 accg[4][4], accu[4][4];
#pragma unroll
  for (int i = 0; i < 4; ++i)
#pragma unroll
    for (int j = 0; j < 4; ++j) { accg[i][j] = vzero; accu[i][j] = vzero; }

  const int wr = wave >> 1, wc = wave & 1;
  const int lrow = lane & 15, kg = lane >> 4;
  const int aoff = (wr * 64 + lrow) * 32 + kg * 8;
  const int boff = (wc * 64 + lrow) * 32 + kg * 8;

  for (int k0 = 0; k0 < H_DIM; k0 += 32) {
    gl_lds16(gX,        ldsX);
    gl_lds16(gX + half, ldsX + 4096);
    gl_lds16(gG,        ldsG);
    gl_lds16(gG + half, ldsG + 4096);
    gl_lds16(gU,        ldsU);
    gl_lds16(gU + half, ldsU + 4096);
    gX += 32; gG += 32; gU += 32;
    __syncthreads();

    bf16x8 a[4], bg[4], bu[4];
#pragma unroll
    for (int f = 0; f < 4; ++f) {
      a[f]  = *(const bf16x8*)(Xs + aoff + f * 16 * 32);
      bg[f] = *(const bf16x8*)(Gs + boff + f * 16 * 32);
      bu[f] = *(const bf16x8*)(Us + boff + f * 16 * 32);
    }
#pragma unroll
    for (int i = 0; i < 4; ++i)
#pragma unroll
      for (int j = 0; j < 4; ++j) {
        accg[i][j] = __builtin_amdgcn_mfma_f32_16x16x32_bf16(a[i], bg[j], accg[i][j], 0, 0, 0);
        accu[i][j] = __builtin_amdgcn_mfma_f32_16x16x32_bf16(a[i], bu[j], accu[i][j], 0, 0, 0);
      }
    __syncthreads();
  }

  // C/D layout: col = lane&15, row = (lane>>4)*4 + e  [m89-verified]
  const int m0 = tm * 128 + wr * 64 + kg * 4;
  const int n0 = tn * 128 + wc * 64 + lrow;
#pragma unroll
  for (int i = 0; i < 4; ++i)
#pragma unroll
    for (int j = 0; j < 4; ++j)
#pragma unroll
      for (int e = 0; e < 4; ++e) {
        float g = accg[i][j][e];
        float u = accu[i][j][e];
        float s = g / (1.0f + __expf(-g));        // silu
        A[(size_t)(m0 + i * 16 + e) * I_DIM + (n0 + j * 16)] = (bf16_t)(s * u);
      }
}

// ---------------------------------------------------------------------------
// Kernel 2: D[M,H] = A Wd^T   (K = I_DIM; bf16 in, fp32 out)
// ---------------------------------------------------------------------------
__global__ __launch_bounds__(256, 2)
void k_down(const bf16_t* __restrict__ Aa, const bf16_t* __restrict__ Wd,
            float* __restrict__ D)
{
  __shared__ bf16_t As_[128 * 32];
  __shared__ bf16_t Bs_[128 * 32];

  const int tid  = threadIdx.x;
  const int wave = tid >> 6;
  const int lane = tid & 63;

  const int TN = H_DIM / 128;              // 32
  const int tm = blockIdx.x / TN;
  const int tn = blockIdx.x % TN;

  const int srow = tid >> 2;
  const int scol = (tid & 3) * 8;

  const bf16_t* gA = Aa + (size_t)(tm * 128 + srow) * I_DIM + scol;
  const bf16_t* gB = Wd + (size_t)(tn * 128 + srow) * I_DIM + scol;
  const size_t half = (size_t)64 * I_DIM;

  char* ldsA = (char*)As_ + wave * 1024;
  char* ldsB = (char*)Bs_ + wave * 1024;

  const f32x4 vzero = {0.f, 0.f, 0.f, 0.f};
  f32x4 acc[4][4];
#pragma unroll
  for (int i = 0; i < 4; ++i)
#pragma unroll
    for (int j = 0; j < 4; ++j) acc[i][j] = vzero;

  const int wr = wave >> 1, wc = wave & 1;
  const int lrow = lane & 15, kg = lane >> 4;
  const int aoff = (wr * 64 + lrow) * 32 + kg * 8;
  const int boff = (wc * 64 + lrow) * 32 + kg * 8;

  for (int k0 = 0; k0 < I_DIM; k0 += 32) {
    gl_lds16(gA,        ldsA);
    gl_lds16(gA + half, ldsA + 4096);
    gl_lds16(gB,        ldsB);
    gl_lds16(gB + half, ldsB + 4096);
    gA += 32; gB += 32;
    __syncthreads();

    bf16x8 a[4], b[4];
#pragma unroll
    for (int f = 0; f < 4; ++f) {
      a[f] = *(const bf16x8*)(As_ + aoff + f * 16 * 32);
      b[f] = *(const bf16x8*)(Bs_ + boff + f * 16 * 32);
    }
#pragma unroll
    for (int i = 0; i < 4; ++i)
#pragma unroll
      for (int j = 0; j < 4; ++j)
        acc[i][j] = __builtin_amdgcn_mfma_f32_16x16x32_bf16(a[i], b[j], acc[i][j], 0, 0, 0);
    __syncthreads();
  }

  const int m0 = tm * 128 + wr * 64 + kg * 4;
  const int n0 = tn * 128 + wc * 64 + lrow;
#pragma unroll
  for (int i = 0; i < 4; ++i)
#pragma unroll
    for (int j = 0; j < 4; ++j)
#pragma unroll
      for (int e = 0; e < 4; ++e)
        D[(size_t)(m0 + i * 16 + e) * H_DIM + (n0 + j * 16)] = acc[i][j][e];
}

// ---------------------------------------------------------------------------
extern "C" void kernel_launch(void* const* d_in, const int* in_sizes, int n_in,
                              void* d_out, int out_size, void* d_ws, size_t ws_size,
                              hipStream_t stream) {
  const float* x  = (const float*)d_in[0];   // [M_TOT, H_DIM] fp32
  const float* wg = (const float*)d_in[1];   // [I_DIM, H_DIM] fp32
  const float* wu = (const float*)d_in[2];   // [I_DIM, H_DIM] fp32
  const float* wd = (const float*)d_in[3];   // [H_DIM, I_DIM] fp32
  float* out = (float*)d_out;                // [M_TOT, H_DIM] fp32

  // ws layout (bf16): A | Xb | Wgb | Wub ; Wdb reuses Wgb region after GEMM1
  const size_t A_BYTES  = (size_t)M_TOT * I_DIM * 2;   // 117,440,512
  const size_t X_BYTES  = (size_t)M_TOT * H_DIM * 2;   //  33,554,432
  const size_t W_BYTES  = (size_t)I_DIM * H_DIM * 2;   // 117,440,512
  char* ws = (char*)d_ws;
  bf16_t* Ab  = (bf16_t*)(ws);
  bf16_t* Xb  = (bf16_t*)(ws + A_BYTES);
  bf16_t* Wgb = (bf16_t*)(ws + A_BYTES + X_BYTES);
  bf16_t* Wub = (bf16_t*)(ws + A_BYTES + X_BYTES + W_BYTES);
  bf16_t* Wdb = Wgb;   // reuse after k_gateup consumed Wgb

  const long nX = (long)M_TOT * H_DIM / 4;
  const long nW = (long)I_DIM * H_DIM / 4;

  k_conv<<<dim3(2048), dim3(256), 0, stream>>>((const float4*)x,  (bf16x4*)Xb,  nX);
  k_conv<<<dim3(2048), dim3(256), 0, stream>>>((const float4*)wg, (bf16x4*)Wgb, nW);
  k_conv<<<dim3(2048), dim3(256), 0, stream>>>((const float4*)wu, (bf16x4*)Wub, nW);

  const int grid1 = (M_TOT / 128) * (I_DIM / 128);  // 3584
  k_gateup<<<dim3(grid1), dim3(256), 0, stream>>>(Xb, Wgb, Wub, Ab);

  k_conv<<<dim3(2048), dim3(256), 0, stream>>>((const float4*)wd, (bf16x4*)Wdb, nW);

  const int grid2 = (M_TOT / 128) * (H_DIM / 128);  // 1024
  k_down<<<dim3(grid2), dim3(256), 0, stream>>>(Ab, Wdb, out);
}

// Round 3
// 1500.901 us; speedup vs baseline: 1.2178x; 1.2178x over previous
//
#include <hip/hip_runtime.h>
#include <hip/hip_bf16.h>
#include <stdint.h>

typedef __bf16 bf16_t;
typedef __bf16 bf16x4 __attribute__((ext_vector_type(4)));
typedef __bf16 bf16x8 __attribute__((ext_vector_type(8)));
typedef float f32x4 __attribute__((ext_vector_type(4)));

#define LDS_CAST(p) ((__attribute__((address_space(3))) void*)(p))
#define GLB_CAST(p) ((const __attribute__((address_space(1))) void*)(p))

__device__ __forceinline__ void gl_lds16(const void* g, void* l) {
  __builtin_amdgcn_global_load_lds(GLB_CAST(g), LDS_CAST(l), 16, 0, 0);
}

#define MFMA16(a,b,c) __builtin_amdgcn_mfma_f32_16x16x32_bf16((a),(b),(c),0,0,0)
#define BARRIER() __builtin_amdgcn_s_barrier()
#define LGKM0() do { asm volatile("s_waitcnt lgkmcnt(0)" ::: "memory"); \
                     __builtin_amdgcn_sched_barrier(0); } while(0)
#define VMW(n)  asm volatile("s_waitcnt vmcnt(" #n ")" ::: "memory")

static constexpr int M_TOT = 4096, H_DIM = 4096, I_DIM = 14336;

// ---------------------------------------------------------------------------
// fp32 -> bf16 conversion (float4 in, bf16x4 out), grid-stride
// ---------------------------------------------------------------------------
__global__ __launch_bounds__(256)
void k_conv(const float4* __restrict__ src, bf16x4* __restrict__ dst, long n4)
{
  long stride = (long)gridDim.x * blockDim.x;
  for (long i = (long)blockIdx.x * blockDim.x + threadIdx.x; i < n4; i += stride) {
    float4 v = src[i];
    bf16x4 o;
    o[0] = (bf16_t)v.x; o[1] = (bf16_t)v.y; o[2] = (bf16_t)v.z; o[3] = (bf16_t)v.w;
    dst[i] = o;
  }
}

// ===========================================================================
// GEMM1: A[M,I] = silu(X Wg^T) * (X Wu^T)
// BM=256, BN=128, BK=32. 8 waves (2M x 4N), per-wave 128x32 out.
// 4 LDS tile-buffers (32 KiB each: A 16K | Bg 8K | Bu 8K), stage lead 3 tiles,
// 2 phases/tile, 2 global_load_lds per phase, vmcnt(8) counted waits.
// st_16x32-style swizzle: byte ^= ((byte>>9)&1)<<5 (read side + pre-swizzled
// global source; linear LDS dest for global_load_lds).
// ===========================================================================
__global__ __launch_bounds__(512, 2)
void k_gateup8(const bf16_t* __restrict__ X, const bf16_t* __restrict__ Wg,
               const bf16_t* __restrict__ Wu, bf16_t* __restrict__ Aout)
{
  __shared__ __align__(1024) char lds[131072];
  const int tid = threadIdx.x, wave = tid >> 6, lane = tid & 63;
  const int lr = lane & 15, kg = lane >> 4;
  const int xm = ((lr >> 3) & 1) << 5;          // read-side swizzle mask (lane-only)
  const int wm = wave >> 2, wn = wave & 3;

  const int bid = blockIdx.x;                   // grid = 16*112 = 1792, %8==0
  const int swz = (bid & 7) * 224 + (bid >> 3); // bijective XCD swizzle
  const int tm = swz / 112, tn = swz % 112;

  // staging: thread t covers unit byte t*16 (8KB units, 1 load each);
  // source col pre-swizzled by the same involution (bit9 of t*16 = (t>>5)&1)
  const int srow  = tid >> 2;                                   // 0..127
  const int scolb = ((tid & 3) * 16) ^ (((tid >> 5) & 1) << 5); // byte col in 64B row

  const bf16_t* gX = X  + (size_t)(tm * 256 + srow) * H_DIM + (scolb >> 1);
  const bf16_t* gG = Wg + (size_t)(tn * 128 + srow) * H_DIM + (scolb >> 1);
  const bf16_t* gU = Wu + (size_t)(tn * 128 + srow) * H_DIM + (scolb >> 1);
  const size_t xh = (size_t)128 * H_DIM;        // A rows 128..255

  // fragment read offsets (within a 32 KiB buffer), swizzle folded in
  const int offA = (wm * 128 + lr) * 64 + ((kg * 16) ^ xm);          // + f*1024
  const int offG = 16384 + (wn * 32 + lr) * 64 + ((kg * 16) ^ xm);   // + n*1024
  const int offU = offG + 8192;

  const f32x4 vz = {0.f, 0.f, 0.f, 0.f};
  f32x4 accg[8][2], accu[8][2];
#pragma unroll
  for (int m = 0; m < 8; ++m)
#pragma unroll
    for (int n = 0; n < 2; ++n) { accg[m][n] = vz; accu[m][n] = vz; }

  // prologue: stage tiles 0..2 into bufs 0..2
#pragma unroll
  for (int t = 0; t < 3; ++t) {
    char* lb = lds + t * 32768 + wave * 1024;
    gl_lds16(gX + t * 32,      lb);
    gl_lds16(gX + xh + t * 32, lb + 8192);
    gl_lds16(gG + t * 32,      lb + 16384);
    gl_lds16(gU + t * 32,      lb + 24576);
  }
  VMW(8); BARRIER();

  bf16x8 bg[2], bu[2];

#define G1_PHA(bb, DO_STG, sb, kc, VMWAIT)                                    \
  {                                                                           \
    bf16x8 a0[4];                                                             \
    _Pragma("unroll") for (int f = 0; f < 4; ++f)                             \
      a0[f] = *(const bf16x8*)((bb) + offA + f * 1024);                       \
    _Pragma("unroll") for (int n = 0; n < 2; ++n) {                           \
      bg[n] = *(const bf16x8*)((bb) + offG + n * 1024);                       \
      bu[n] = *(const bf16x8*)((bb) + offU + n * 1024); }                     \
    if (DO_STG) { gl_lds16(gX + (kc), (sb));                                  \
                  gl_lds16(gX + xh + (kc), (sb) + 8192); }                    \
    BARRIER(); LGKM0();                                                       \
    __builtin_amdgcn_s_setprio(1);                                            \
    _Pragma("unroll") for (int m = 0; m < 4; ++m)                             \
    _Pragma("unroll") for (int n = 0; n < 2; ++n) {                           \
      accg[m][n] = MFMA16(a0[m], bg[n], accg[m][n]);                          \
      accu[m][n] = MFMA16(a0[m], bu[n], accu[m][n]); }                        \
    __builtin_amdgcn_s_setprio(0);                                            \
    VMWAIT; BARRIER();                                                        \
  }

#define G1_PHB(bb, DO_STG, sb, kc, VMWAIT)                                    \
  {                                                                           \
    bf16x8 a1[4];                                                             \
    _Pragma("unroll") for (int f = 0; f < 4; ++f)                             \
      a1[f] = *(const bf16x8*)((bb) + offA + (f + 4) * 1024);                 \
    if (DO_STG) { gl_lds16(gG + (kc), (sb) + 16384);                          \
                  gl_lds16(gU + (kc), (sb) + 24576); }                        \
    BARRIER(); LGKM0();                                                       \
    __builtin_amdgcn_s_setprio(1);                                            \
    _Pragma("unroll") for (int m = 0; m < 4; ++m)                             \
    _Pragma("unroll") for (int n = 0; n < 2; ++n) {                           \
      accg[4 + m][n] = MFMA16(a1[m], bg[n], accg[4 + m][n]);                  \
      accu[4 + m][n] = MFMA16(a1[m], bu[n], accu[4 + m][n]); }                \
    __builtin_amdgcn_s_setprio(0);                                            \
    VMWAIT; BARRIER();                                                        \
  }

  const int NT = H_DIM / 32;                    // 128
  for (int T = 0; T < NT - 3; ++T) {
    const char* bb = lds + (T & 3) * 32768;
    char* sb = lds + ((T + 3) & 3) * 32768 + wave * 1024;
    const int kc = (T + 3) * 32;
    G1_PHA(bb, true, sb, kc, VMW(8));
    G1_PHB(bb, true, sb, kc, VMW(8));
  }
  { const char* bb = lds + ((NT-3) & 3) * 32768;  // drain 8 -> 4 -> 0
    G1_PHA(bb, false, lds, 0, VMW(4)); G1_PHB(bb, false, lds, 0, VMW(4)); }
  { const char* bb = lds + ((NT-2) & 3) * 32768;
    G1_PHA(bb, false, lds, 0, VMW(0)); G1_PHB(bb, false, lds, 0, VMW(0)); }
  { const char* bb = lds + ((NT-1) & 3) * 32768;
    G1_PHA(bb, false, lds, 0, VMW(0)); G1_PHB(bb, false, lds, 0, VMW(0)); }

  // epilogue: C/D layout col = lr, row = kg*4 + e
  const int r0 = tm * 256 + wm * 128 + kg * 4;
  const int c0 = tn * 128 + wn * 32 + lr;
#pragma unroll
  for (int m = 0; m < 8; ++m)
#pragma unroll
    for (int n = 0; n < 2; ++n)
#pragma unroll
      for (int e = 0; e < 4; ++e) {
        float g = accg[m][n][e];
        float u = accu[m][n][e];
        float s = g / (1.0f + __expf(-g));
        Aout[(size_t)(r0 + m * 16 + e) * I_DIM + c0 + n * 16] = (bf16_t)(s * u);
      }
#undef G1_PHA
#undef G1_PHB
}

// ===========================================================================
// GEMM2: D[M,H] = A Wd^T.  BM=BN=256, BK=32, K=I_DIM.
// Same pipeline: 4 bufs x 32 KiB (A[256][32] 16K | B[256][32] 16K),
// per-wave 128x64 out, acc[8][4].
// ===========================================================================
__global__ __launch_bounds__(512, 2)
void k_down8(const bf16_t* __restrict__ Aa, const bf16_t* __restrict__ Wd,
             float* __restrict__ D)
{
  __shared__ __align__(1024) char lds[131072];
  const int tid = threadIdx.x, wave = tid >> 6, lane = tid & 63;
  const int lr = lane & 15, kg = lane >> 4;
  const int xm = ((lr >> 3) & 1) << 5;
  const int wm = wave >> 2, wn = wave & 3;

  const int bid = blockIdx.x;                   // grid = 256, %8==0
  const int swz = (bid & 7) * 32 + (bid >> 3);
  const int tm = swz >> 4, tn = swz & 15;

  const int srow  = tid >> 2;                                   // 0..127
  const int scolb = ((tid & 3) * 16) ^ (((tid >> 5) & 1) << 5);

  const bf16_t* gA = Aa + (size_t)(tm * 256 + srow) * I_DIM + (scolb >> 1);
  const bf16_t* gB = Wd + (size_t)(tn * 256 + srow) * I_DIM + (scolb >> 1);
  const size_t hI = (size_t)128 * I_DIM;

  const int offA = (wm * 128 + lr) * 64 + ((kg * 16) ^ xm);          // + f*1024
  const int offB = 16384 + (wn * 64 + lr) * 64 + ((kg * 16) ^ xm);   // + n*1024

  const f32x4 vz = {0.f, 0.f, 0.f, 0.f};
  f32x4 acc[8][4];
#pragma unroll
  for (int m = 0; m < 8; ++m)
#pragma unroll
    for (int n = 0; n < 4; ++n) acc[m][n] = vz;

  // prologue: tiles 0..2
#pragma unroll
  for (int t = 0; t < 3; ++t) {
    char* lb = lds + t * 32768 + wave * 1024;
    gl_lds16(gA + t * 32,      lb);
    gl_lds16(gA + hI + t * 32, lb + 8192);
    gl_lds16(gB + t * 32,      lb + 16384);
    gl_lds16(gB + hI + t * 32, lb + 24576);
  }
  VMW(8); BARRIER();

  bf16x8 bfr[4];

#define G2_PHA(bb, DO_STG, sb, kc, VMWAIT)                                    \
  {                                                                           \
    bf16x8 a0[4];                                                             \
    _Pragma("unroll") for (int f = 0; f < 4; ++f)                             \
      a0[f] = *(const bf16x8*)((bb) + offA + f * 1024);                       \
    _Pragma("unroll") for (int n = 0; n < 4; ++n)                             \
      bfr[n] = *(const bf16x8*)((bb) + offB + n * 1024);                      \
    if (DO_STG) { gl_lds16(gA + (kc), (sb));                                  \
                  gl_lds16(gA + hI + (kc), (sb) + 8192); }                    \
    BARRIER(); LGKM0();                                                       \
    __builtin_amdgcn_s_setprio(1);                                            \
    _Pragma("unroll") for (int m = 0; m < 4; ++m)                             \
    _Pragma("unroll") for (int n = 0; n < 4; ++n)                             \
      acc[m][n] = MFMA16(a0[m], bfr[n], acc[m][n]);                           \
    __builtin_amdgcn_s_setprio(0);                                            \
    VMWAIT; BARRIER();                                                        \
  }

#define G2_PHB(bb, DO_STG, sb, kc, VMWAIT)                                    \
  {                                                                           \
    bf16x8 a1[4];                                                             \
    _Pragma("unroll") for (int f = 0; f < 4; ++f)                             \
      a1[f] = *(const bf16x8*)((bb) + offA + (f + 4) * 1024);                 \
    if (DO_STG) { gl_lds16(gB + (kc), (sb) + 16384);                          \
                  gl_lds16(gB + hI + (kc), (sb) + 24576); }                   \
    BARRIER(); LGKM0();                                                       \
    __builtin_amdgcn_s_setprio(1);                                            \
    _Pragma("unroll") for (int m = 0; m < 4; ++m)                             \
    _Pragma("unroll") for (int n = 0; n < 4; ++n)                             \
      acc[4 + m][n] = MFMA16(a1[m], bfr[n], acc[4 + m][n]);                   \
    __builtin_amdgcn_s_setprio(0);                                            \
    VMWAIT; BARRIER();                                                        \
  }

  const int NT = I_DIM / 32;                    // 448
  for (int T = 0; T < NT - 3; ++T) {
    const char* bb = lds + (T & 3) * 32768;
    char* sb = lds + ((T + 3) & 3) * 32768 + wave * 1024;
    const int kc = (T + 3) * 32;
    G2_PHA(bb, true, sb, kc, VMW(8));
    G2_PHB(bb, true, sb, kc, VMW(8));
  }
  { const char* bb = lds + ((NT-3) & 3) * 32768;
    G2_PHA(bb, false, lds, 0, VMW(4)); G2_PHB(bb, false, lds, 0, VMW(4)); }
  { const char* bb = lds + ((NT-2) & 3) * 32768;
    G2_PHA(bb, false, lds, 0, VMW(0)); G2_PHB(bb, false, lds, 0, VMW(0)); }
  { const char* bb = lds + ((NT-1) & 3) * 32768;
    G2_PHA(bb, false, lds, 0, VMW(0)); G2_PHB(bb, false, lds, 0, VMW(0)); }

  const int r0 = tm * 256 + wm * 128 + kg * 4;
  const int c0 = tn * 256 + wn * 64 + lr;
#pragma unroll
  for (int m = 0; m < 8; ++m)
#pragma unroll
    for (int n = 0; n < 4; ++n)
#pragma unroll
      for (int e = 0; e < 4; ++e)
        D[(size_t)(r0 + m * 16 + e) * H_DIM + c0 + n * 16] = acc[m][n][e];
#undef G2_PHA
#undef G2_PHB
}

// ---------------------------------------------------------------------------
extern "C" void kernel_launch(void* const* d_in, const int* in_sizes, int n_in,
                              void* d_out, int out_size, void* d_ws, size_t ws_size,
                              hipStream_t stream) {
  const float* x  = (const float*)d_in[0];
  const float* wg = (const float*)d_in[1];
  const float* wu = (const float*)d_in[2];
  const float* wd = (const float*)d_in[3];
  float* out = (float*)d_out;

  const size_t A_BYTES = (size_t)M_TOT * I_DIM * 2;
  const size_t X_BYTES = (size_t)M_TOT * H_DIM * 2;
  const size_t W_BYTES = (size_t)I_DIM * H_DIM * 2;
  char* ws = (char*)d_ws;
  bf16_t* Ab  = (bf16_t*)(ws);
  bf16_t* Xb  = (bf16_t*)(ws + A_BYTES);
  bf16_t* Wgb = (bf16_t*)(ws + A_BYTES + X_BYTES);
  bf16_t* Wub = (bf16_t*)(ws + A_BYTES + X_BYTES + W_BYTES);
  bf16_t* Wdb = Wgb;   // reuse after k_gateup8 consumed Wgb

  const long nX = (long)M_TOT * H_DIM / 4;
  const long nW = (long)I_DIM * H_DIM / 4;

  k_conv<<<dim3(2048), dim3(256), 0, stream>>>((const float4*)x,  (bf16x4*)Xb,  nX);
  k_conv<<<dim3(2048), dim3(256), 0, stream>>>((const float4*)wg, (bf16x4*)Wgb, nW);
  k_conv<<<dim3(2048), dim3(256), 0, stream>>>((const float4*)wu, (bf16x4*)Wub, nW);

  k_gateup8<<<dim3(16 * 112), dim3(512), 0, stream>>>(Xb, Wgb, Wub, Ab);

  k_conv<<<dim3(2048), dim3(256), 0, stream>>>((const float4*)wd, (bf16x4*)Wdb, nW);

  k_down8<<<dim3(16 * 16), dim3(512), 0, stream>>>(Ab, Wdb, out);
}